// Round 2
// baseline (356.363 us; speedup 1.0000x reference)
//
#include <hip/hip_runtime.h>
#include <stdint.h>

// KMeans top-2 distance gap: N=1M x D=64, K=128, fp32.
// S = X*C^T via bf16 MFMA 16x16x32; d2 = csq - 2s (||x||^2 cancels in the gap).
// R2: 2 groups per wave (7813 blocks), both x-tiles loaded up front to hide
// HBM latency; was 2048 blocks x 7.6 serial dependent iterations.

#define DD 64
#define KK 128

typedef __attribute__((ext_vector_type(8))) short bf16x8;
typedef __attribute__((ext_vector_type(4))) float f32x4;
typedef __attribute__((ext_vector_type(4))) unsigned int u32x4;

__device__ __forceinline__ uint32_t pk_bf16(float a, float b) {
  uint32_t ua = __builtin_bit_cast(uint32_t, a);
  uint32_t ub = __builtin_bit_cast(uint32_t, b);
  ua += 0x7fffu + ((ua >> 16) & 1u);   // RNE
  ub += 0x7fffu + ((ub >> 16) & 1u);
  return (ua >> 16) | (ub & 0xffff0000u);
}

// One 16-row group: pack A, 16 MFMA, top-2 epilogue, store gap.
__device__ __forceinline__ void process_group(
    int g, int N, int q, int li,
    const bf16x8* bfr, const float* cs,
    float4 f0, float4 f1, float4 f2, float4 f3,
    float* __restrict__ out) {
  u32x4 ua, ub;
  ua.x = pk_bf16(f0.x, f0.y);
  ua.y = pk_bf16(f0.z, f0.w);
  ua.z = pk_bf16(f1.x, f1.y);
  ua.w = pk_bf16(f1.z, f1.w);
  ub.x = pk_bf16(f2.x, f2.y);
  ub.y = pk_bf16(f2.z, f2.w);
  ub.z = pk_bf16(f3.x, f3.y);
  ub.w = pk_bf16(f3.z, f3.w);
  bf16x8 A0 = __builtin_bit_cast(bf16x8, ua);
  bf16x8 A1 = __builtin_bit_cast(bf16x8, ub);

  f32x4 acc[8];
  #pragma unroll
  for (int t = 0; t < 8; ++t) acc[t] = (f32x4){0.f, 0.f, 0.f, 0.f};
  #pragma unroll
  for (int t = 0; t < 8; ++t) {
    acc[t] = __builtin_amdgcn_mfma_f32_16x16x32_bf16(A0, bfr[2 * t], acc[t], 0, 0, 0);
    acc[t] = __builtin_amdgcn_mfma_f32_16x16x32_bf16(A1, bfr[2 * t + 1], acc[t], 0, 0, 0);
  }

  // lane holds D[row=q*4+r][col=li+16t]; top-2 min per row
  float res1[4], res2[4];
  #pragma unroll
  for (int r = 0; r < 4; ++r) {
    float m1 = 3.4e38f, m2 = 3.4e38f;
    #pragma unroll
    for (int t = 0; t < 8; ++t) {
      float d = fmaf(-2.f, acc[t][r], cs[t]);
      float lo = fminf(m1, d);
      m2 = fminf(m2, fmaxf(m1, d));
      m1 = lo;
    }
    #pragma unroll
    for (int m = 1; m < 16; m <<= 1) {   // xor<16 stays inside the quad
      float o1 = __shfl_xor(m1, m, 64);
      float o2 = __shfl_xor(m2, m, 64);
      float lo = fminf(m1, o1);
      m2 = fminf(fminf(m2, o2), fmaxf(m1, o1));
      m1 = lo;
    }
    res1[r] = m1;
    res2[r] = m2;
  }

  if (li < 4) {
    int prow = g * 16 + q * 4 + li;
    if (prow < N) {
      float v1 = li == 0 ? res1[0] : li == 1 ? res1[1] : li == 2 ? res1[2] : res1[3];
      float v2 = li == 0 ? res2[0] : li == 1 ? res2[1] : li == 2 ? res2[2] : res2[3];
      out[prow] = v2 - v1;
    }
  }
}

__global__ __launch_bounds__(256, 3) void kmeans_top2_kernel(
    const float* __restrict__ x, const float* __restrict__ cent,
    float* __restrict__ out, int N, int ngroups) {
  // B fragments, fragment-ordered: slot th = t*2+h; lane l supplies
  // B[k=(l>>4)*8+j + 32h][col=(l&15)+16t] = cent[col][k]
  __shared__ uint32_t fragB[16 * 64 * 4];  // 16 KB
  __shared__ float csq_lds[KK];

  const int tid = threadIdx.x;

  // ---- phase 1: centroids -> bf16 fragments + fp32 sq-norms (once/block) ----
  #pragma unroll
  for (int i = 0; i < 4; ++i) {
    int s = tid + i * 256;
    int l = s & 63;
    int th = s >> 6;
    int t = th >> 1, h = th & 1;
    int c = (l & 15) + 16 * t;
    int kb = ((l >> 4) << 3) + 32 * h;
    const float4* p = (const float4*)(cent + c * DD + kb);
    float4 f0 = p[0];
    float4 f1 = p[1];
    uint32_t* dst = &fragB[s * 4];
    dst[0] = pk_bf16(f0.x, f0.y);
    dst[1] = pk_bf16(f0.z, f0.w);
    dst[2] = pk_bf16(f1.x, f1.y);
    dst[3] = pk_bf16(f1.z, f1.w);
  }
  if (tid < KK) {
    const float4* p = (const float4*)(cent + tid * DD);
    float s = 0.f;
    #pragma unroll
    for (int i = 0; i < 16; ++i) {
      float4 f = p[i];
      s = fmaf(f.x, f.x, s);
      s = fmaf(f.y, f.y, s);
      s = fmaf(f.z, f.z, s);
      s = fmaf(f.w, f.w, s);
    }
    csq_lds[tid] = s;
  }
  __syncthreads();

  const int lane = tid & 63;
  const int q = lane >> 4;
  const int li = lane & 15;
  const int gwave = blockIdx.x * 4 + (tid >> 6);
  const int g0 = gwave * 2;
  const int g1 = g0 + 1;

  // ---- issue BOTH groups' x loads up front (independent, overlap latency) ----
  int row0 = g0 * 16 + li;
  row0 = row0 < N ? row0 : N - 1;
  const float4* p0 = (const float4*)(x + (size_t)row0 * DD + q * 8);
  float4 a0 = p0[0], a1 = p0[1], a2 = p0[8], a3 = p0[9];
  int row1 = g1 * 16 + li;
  row1 = row1 < N ? row1 : N - 1;
  const float4* p1 = (const float4*)(x + (size_t)row1 * DD + q * 8);
  float4 b0 = p1[0], b1 = p1[1], b2 = p1[8], b3 = p1[9];

  // ---- B fragments + csq into registers ----
  bf16x8 bfr[16];
  #pragma unroll
  for (int th = 0; th < 16; ++th)
    bfr[th] = *(const bf16x8*)&fragB[(th * 64 + lane) * 4];
  float cs[8];
  #pragma unroll
  for (int t = 0; t < 8; ++t) cs[t] = csq_lds[t * 16 + li];

  if (g0 < ngroups) process_group(g0, N, q, li, bfr, cs, a0, a1, a2, a3, out);
  if (g1 < ngroups) process_group(g1, N, q, li, bfr, cs, b0, b1, b2, b3, out);
}

extern "C" void kernel_launch(void* const* d_in, const int* in_sizes, int n_in,
                              void* d_out, int out_size, void* d_ws, size_t ws_size,
                              hipStream_t stream) {
  const float* x = (const float*)d_in[0];
  const float* cent = (const float*)d_in[1];
  float* out = (float*)d_out;
  int N = in_sizes[0] / DD;
  int ngroups = (N + 15) / 16;               // 62500
  int nblocks = (ngroups + 7) / 8;           // 2 groups per wave, 4 waves/block
  kmeans_top2_kernel<<<dim3(nblocks), dim3(256), 0, stream>>>(x, cent, out, N, ngroups);
}

// Round 3
// 342.034 us; speedup vs baseline: 1.0419x; 1.0419x over previous
//
#include <hip/hip_runtime.h>
#include <stdint.h>

// KMeans top-2 distance gap: N=1M x D=64, K=128, fp32.
// R3: operand-swapped MFMA — A=centroid fragments, B=point fragments
// (register data identical to R1's fragments, just swapped call slots).
// D[row=centroid][col=point] => each lane owns ONE point's 32 distances:
// top-2 via min+med3 insert (2 ops/val), cross-lane merge only xor16/xor32.
// Grid back to 2048 blocks (setup amortization) + next-group x prefetch.

#define DD 64
#define KK 128

typedef __attribute__((ext_vector_type(8))) short bf16x8;
typedef __attribute__((ext_vector_type(4))) float f32x4;
typedef __attribute__((ext_vector_type(4))) unsigned int u32x4;

__device__ __forceinline__ uint32_t pk_bf16(float a, float b) {
  uint32_t ua = __builtin_bit_cast(uint32_t, a);
  uint32_t ub = __builtin_bit_cast(uint32_t, b);
  ua += 0x7fffu + ((ua >> 16) & 1u);   // RNE
  ub += 0x7fffu + ((ub >> 16) & 1u);
  return (ua >> 16) | (ub & 0xffff0000u);
}

__global__ __launch_bounds__(256, 3) void kmeans_top2_kernel(
    const float* __restrict__ x, const float* __restrict__ cent,
    float* __restrict__ out, int N, int ngroups) {
  // Centroid fragments, slot th = t*2+h: lane l holds
  // cent[(l&15)+16t][(l>>4)*8+j+32h], j=0..7 — valid as the A operand of
  // mfma_f32_16x16x32_bf16 (A[m=l&15][k=(l>>4)*8+j]).
  __shared__ uint32_t fragB[16 * 64 * 4];  // 16 KB
  __shared__ float csq_lds[KK];

  const int tid = threadIdx.x;

  // ---- phase 1: centroids -> bf16 fragments + fp32 sq-norms (once/block) ----
  #pragma unroll
  for (int i = 0; i < 4; ++i) {
    int s = tid + i * 256;
    int l = s & 63;
    int th = s >> 6;
    int t = th >> 1, h = th & 1;
    int c = (l & 15) + 16 * t;
    int kb = ((l >> 4) << 3) + 32 * h;
    const float4* p = (const float4*)(cent + c * DD + kb);
    float4 f0 = p[0];
    float4 f1 = p[1];
    uint32_t* dst = &fragB[s * 4];
    dst[0] = pk_bf16(f0.x, f0.y);
    dst[1] = pk_bf16(f0.z, f0.w);
    dst[2] = pk_bf16(f1.x, f1.y);
    dst[3] = pk_bf16(f1.z, f1.w);
  }
  if (tid < KK) {
    const float4* p = (const float4*)(cent + tid * DD);
    float s = 0.f;
    #pragma unroll
    for (int i = 0; i < 16; ++i) {
      float4 f = p[i];
      s = fmaf(f.x, f.x, s);
      s = fmaf(f.y, f.y, s);
      s = fmaf(f.z, f.z, s);
      s = fmaf(f.w, f.w, s);
    }
    csq_lds[tid] = s;
  }
  __syncthreads();

  const int lane = tid & 63;
  const int q = lane >> 4;
  const int li = lane & 15;
  const int gwave = blockIdx.x * 4 + (tid >> 6);
  const int nwaves = gridDim.x * 4;

  // centroid fragments + per-lane csq (c = 16t + q*4 + r, contiguous x4)
  bf16x8 cfr[16];
  #pragma unroll
  for (int th = 0; th < 16; ++th)
    cfr[th] = *(const bf16x8*)&fragB[(th * 64 + lane) * 4];
  f32x4 cs[8];
  #pragma unroll
  for (int t = 0; t < 8; ++t)
    cs[t] = *(const f32x4*)&csq_lds[16 * t + q * 4];

  const int glast = ngroups - 1;

  // point-tile load: lane (q,li) holds x[pt=g*16+li][k=q*8..+8, 32+q*8..+8]
  auto ldx = [&](int gg, float4& f0, float4& f1, float4& f2, float4& f3) {
    int row = gg * 16 + li;
    row = row < N ? row : N - 1;
    const float4* p = (const float4*)(x + (size_t)row * DD + q * 8);
    f0 = p[0];
    f1 = p[1];
    f2 = p[8];
    f3 = p[9];
  };

  float4 c0, c1, c2, c3;
  if (gwave < ngroups) ldx(gwave, c0, c1, c2, c3);

  for (int g = gwave; g < ngroups; g += nwaves) {
    // prefetch next group's x-tile (registers), clamp to valid group
    int gn = g + nwaves;
    gn = gn < glast ? gn : glast;
    float4 n0, n1, n2, n3;
    ldx(gn, n0, n1, n2, n3);

    // pack current point tile to bf16 B-fragments
    u32x4 ua, ub;
    ua.x = pk_bf16(c0.x, c0.y);
    ua.y = pk_bf16(c0.z, c0.w);
    ua.z = pk_bf16(c1.x, c1.y);
    ua.w = pk_bf16(c1.z, c1.w);
    ub.x = pk_bf16(c2.x, c2.y);
    ub.y = pk_bf16(c2.z, c2.w);
    ub.z = pk_bf16(c3.x, c3.y);
    ub.w = pk_bf16(c3.z, c3.w);
    bf16x8 P0 = __builtin_bit_cast(bf16x8, ua);
    bf16x8 P1 = __builtin_bit_cast(bf16x8, ub);

    f32x4 acc[8];
    #pragma unroll
    for (int t = 0; t < 8; ++t) acc[t] = (f32x4){0.f, 0.f, 0.f, 0.f};
    #pragma unroll
    for (int t = 0; t < 8; ++t) {
      acc[t] = __builtin_amdgcn_mfma_f32_16x16x32_bf16(cfr[2 * t], P0, acc[t], 0, 0, 0);
      acc[t] = __builtin_amdgcn_mfma_f32_16x16x32_bf16(cfr[2 * t + 1], P1, acc[t], 0, 0, 0);
    }

    // lane owns point li: 32 distances (t=0..7, r=0..3), c = 16t + q*4 + r
    float m1 = 3.4e38f, m2 = 3.4e38f;
    #pragma unroll
    for (int t = 0; t < 8; ++t) {
      #pragma unroll
      for (int r = 0; r < 4; ++r) {
        float d = fmaf(-2.f, acc[t][r], cs[t][r]);
        m2 = __builtin_amdgcn_fmed3f(m1, m2, d);  // insert: new m2
        m1 = fminf(m1, d);                        // insert: new m1
      }
    }
    // merge sorted pairs across q (lanes l, l^16, l^32, l^48 share point li)
    #pragma unroll
    for (int m = 16; m <= 32; m <<= 1) {
      float o1 = __shfl_xor(m1, m, 64);
      float o2 = __shfl_xor(m2, m, 64);
      float hi = fmaxf(m1, o1);
      m1 = fminf(m1, o1);
      m2 = fminf(fminf(m2, o2), hi);
    }

    if (q == 0) {
      int prow = g * 16 + li;
      if (prow < N) out[prow] = m2 - m1;
    }

    c0 = n0;
    c1 = n1;
    c2 = n2;
    c3 = n3;
  }
}

extern "C" void kernel_launch(void* const* d_in, const int* in_sizes, int n_in,
                              void* d_out, int out_size, void* d_ws, size_t ws_size,
                              hipStream_t stream) {
  const float* x = (const float*)d_in[0];
  const float* cent = (const float*)d_in[1];
  float* out = (float*)d_out;
  int N = in_sizes[0] / DD;
  int ngroups = (N + 15) / 16;   // 62500
  kmeans_top2_kernel<<<dim3(2048), dim3(256), 0, stream>>>(x, cent, out, N, ngroups);
}